// Round 10
// baseline (111.223 us; speedup 1.0000x reference)
//
#include <hip/hip_runtime.h>

// InvWarpFlow: out[b,y,x,c] = bilinear(img[b], (y + flow[b,y,x,0], x + flow[b,y,x,1]))
// img: [16,256,512,32] f32 ; flow: [16,256,512,2] f32 ; out: [16,256,512,32] f32
//
// R9 lesson: 4/16/32-deep MLP all saturate at ~99us -> the wall is per-CU
// gather segment-processing rate (TA/L1), ~58 cyc per divergent wave-load.
// This round: LDS-staged band gather. Block stages 24 rows x 24 px x 128B
// img band (72KB, contiguous global_load_lds streams) + 16x16 flow tile
// (2KB); data-dependent reads become ds_read_b128. Rare out-of-band pixels
// (P(|N|>~4)) take a correct global fallback.

typedef float floatx4 __attribute__((ext_vector_type(4)));
typedef float floatx2 __attribute__((ext_vector_type(2)));

__global__ __launch_bounds__(256) void InvWarpFlow_kernel(
    const float* __restrict__ img,
    const float* __restrict__ flow,
    float* __restrict__ out)
{
    constexpr int H = 256, W = 512, C = 32;
    constexpr int TW = 16, RPT = 16;           // core tile: 16 px x 16 rows
    constexpr int BW = 24, NR = 24;            // staged band: 24 px x 24 rows
    constexpr int TILES_X = W / TW;            // 32
    constexpr int TILES_Y = H / RPT;           // 16
    constexpr int NBLK = 16 * TILES_X * TILES_Y; // 8192
    constexpr int PER_XCD = NBLK / 8;          // 1024

    __shared__ float simg[NR * BW * 32];       // 73728 B
    __shared__ float sflow[RPT * TW * 2];      // 2048 B

    // XCD-chunked swizzle; tx fastest (x-adjacent bands share margin columns).
    int bid = blockIdx.x;
    int logical = (bid & 7) * PER_XCD + (bid >> 3);
    int tx = logical & (TILES_X - 1);
    int r  = logical >> 5;
    int ty = r & (TILES_Y - 1);
    int b  = r >> 4;

    int x0 = tx * TW;
    int y0 = ty * RPT;
    int by0 = min(max(y0 - 4, 0), H - NR);     // band rows  [by0, by0+23] all valid
    int bx0 = min(max(x0 - 4, 0), W - BW);     // band cols  [bx0, bx0+23] all valid

    int t = threadIdx.x;

    // ---- Stage img band: 24 rows x 3072 B, linear into LDS.
    // chunk o16 (16B units): row = o16/192, within-row w16 = o16%192.
    {
        const float* gband = img + (((size_t)(b * H + by0)) * W + bx0) * C;
        #pragma unroll
        for (int it = 0; it < 18; ++it) {
            int o16 = it * 256 + t;
            int row = o16 / 192;
            int w16 = o16 - row * 192;
            const float* src = gband + (size_t)row * (W * C) + w16 * 4;
            float* dst = simg + (size_t)(it * 256 + (t & ~63)) * 4;  // wave-uniform base
            __builtin_amdgcn_global_load_lds(
                (const __attribute__((address_space(1))) float*)src,
                (__attribute__((address_space(3))) float*)dst, 16, 0, 0);
        }
    }
    // ---- Stage flow tile: 16 rows x 16 px x 8 B = 128 chunks (waves 0-1).
    if (t < 128) {
        int row = t >> 3;                      // 0..15
        int w16 = t & 7;                       // 2 px per 16B chunk
        const float* src = flow + (((size_t)(b * H + y0 + row)) * W + x0 + w16 * 2) * 2;
        float* dst = sflow + (size_t)(t & ~63) * 4;                  // wave-uniform base
        __builtin_amdgcn_global_load_lds(
            (const __attribute__((address_space(1))) float*)src,
            (__attribute__((address_space(3))) float*)dst, 16, 0, 0);
    }

    asm volatile("s_waitcnt vmcnt(0)" ::: "memory");
    __syncthreads();

    // ---- Compute: thread = (half, px, cg); 8 rows each.
    int cg   = t & 7;
    int px   = (t >> 3) & 15;
    int half = t >> 7;
    int x    = x0 + px;

    #pragma unroll
    for (int k = 0; k < 8; ++k) {
        int yrow = half * 8 + k;
        int y = y0 + yrow;
        floatx2 f = *reinterpret_cast<const floatx2*>(sflow + (yrow * TW + px) * 2);
        float qy = (float)y + f.x;
        float qx = (float)x + f.y;
        float fy = fminf(fmaxf(floorf(qy), 0.0f), (float)(H - 2));
        float fx = fminf(fmaxf(floorf(qx), 0.0f), (float)(W - 2));
        float ay = fminf(fmaxf(qy - fy, 0.0f), 1.0f);
        float ax = fminf(fmaxf(qx - fx, 0.0f), 1.0f);
        int iy = (int)fy;
        int ix = (int)fx;

        floatx4 tl, tr, bl, br;
        if (iy >= by0 && iy <= by0 + NR - 2 && ix >= bx0 && ix <= bx0 + BW - 2) {
            const float* p = simg + ((size_t)(iy - by0) * BW + (ix - bx0)) * 32 + cg * 4;
            tl = *reinterpret_cast<const floatx4*>(p);
            tr = *reinterpret_cast<const floatx4*>(p + 32);
            bl = *reinterpret_cast<const floatx4*>(p + BW * 32);
            br = *reinterpret_cast<const floatx4*>(p + BW * 32 + 32);
        } else {
            const float* g = img + (((size_t)(b * H + iy)) * W + ix) * C + cg * 4;
            tl = *reinterpret_cast<const floatx4*>(g);
            tr = *reinterpret_cast<const floatx4*>(g + C);
            bl = *reinterpret_cast<const floatx4*>(g + (size_t)W * C);
            br = *reinterpret_cast<const floatx4*>(g + (size_t)W * C + C);
        }

        floatx4 top = tl + (tr - tl) * ax;
        floatx4 bot = bl + (br - bl) * ax;
        floatx4 o   = top + (bot - top) * ay;
        __builtin_nontemporal_store(
            o, reinterpret_cast<floatx4*>(out + (((size_t)(b * H + y)) * W + x) * C + cg * 4));
    }
}

extern "C" void kernel_launch(void* const* d_in, const int* in_sizes, int n_in,
                              void* d_out, int out_size, void* d_ws, size_t ws_size,
                              hipStream_t stream) {
    const float* img  = (const float*)d_in[0];
    const float* flow = (const float*)d_in[1];
    float* out = (float*)d_out;

    constexpr int NBLK = 8192;
    InvWarpFlow_kernel<<<NBLK, 256, 0, stream>>>(img, flow, out);
}